// Round 3
// baseline (74.317 us; speedup 1.0000x reference)
//
#include <hip/hip_runtime.h>

typedef __attribute__((ext_vector_type(8)))  __bf16 bf16x8;
typedef __attribute__((ext_vector_type(4)))  __bf16 bf16x4;
typedef __attribute__((ext_vector_type(16))) float  f32x16;

#define D_IN  128
#define N_OUT 32
#define K129  129
#define WROW  16512          // 128*129 floats per W row
#define KE    144            // extended K for W: 128 + 16 (col 128 = wlin, rest 0)
#define NT    16             // m-tiles (32 rows each) per block = 512 rows
#define XQ_ELEMS (16384 * 128)
#define WQ_ELEMS (32 * 128 * KE)

// ---- prep: x -> bf16 [16384][128], pure vectorized copy-convert ----
__global__ void prep_x(const float* __restrict__ x, __bf16* __restrict__ xq) {
    int t = blockIdx.x * 256 + threadIdx.x;              // 262144 threads x 8 elems
    const float4* src = reinterpret_cast<const float4*>(x) + (size_t)t * 2;
    float4 a = src[0], b = src[1];
    bf16x8 v = { (__bf16)a.x, (__bf16)a.y, (__bf16)a.z, (__bf16)a.w,
                 (__bf16)b.x, (__bf16)b.y, (__bf16)b.z, (__bf16)b.w };
    *(reinterpret_cast<bf16x8*>(xq) + t) = v;
}

// ---- prep: W -> bf16 [32][128][144]  (k=128 -> wlin, 129..143 -> 0) ----
__global__ void prep_w(const float* __restrict__ W, __bf16* __restrict__ Wq) {
    for (int e = blockIdx.x * 256 + threadIdx.x; e < WQ_ELEMS; e += gridDim.x * 256) {
        int oi = e / KE, k = e - oi * KE;                // oi = o*128 + i
        int o = oi >> 7, i = oi & 127;
        float v = 0.f;
        if (k <= D_IN) v = W[o * WROW + i * K129 + k];   // k==128 is wlin
        Wq[e] = (__bf16)v;
    }
}

// Load one m-tile's B fragments (ks 0..7 only; ks=8 is a compile-time const)
// plus the epilogue xe chunks.
// B frag (32x32x16): lane l -> col b = l&31, k = (l>>5)*8 + r (contiguous 8 bf16).
// xe chunk (ct,q): 4 bf16 at i = (sub*2+ct)*32 + q*8 + (l>>5)*4.
template<int PREP>
__device__ __forceinline__ void load_tile(
    bf16x8 (&B)[8], bf16x4 (&X)[2][4],
    const __bf16* __restrict__ xq, const float* __restrict__ x,
    long row, int sub, int hi)
{
    if (PREP) {
        const __bf16* xr = xq + row * D_IN;
        #pragma unroll
        for (int ks = 0; ks < 8; ++ks)
            B[ks] = *reinterpret_cast<const bf16x8*>(xr + ks * 16 + hi * 8);
        #pragma unroll
        for (int ct = 0; ct < 2; ++ct)
            #pragma unroll
            for (int q = 0; q < 4; ++q)
                X[ct][q] = *reinterpret_cast<const bf16x4*>(xr + (sub * 2 + ct) * 32 + q * 8 + hi * 4);
    } else {
        const float* xr = x + row * D_IN;
        #pragma unroll
        for (int ks = 0; ks < 8; ++ks) {
            bf16x8 f;
            #pragma unroll
            for (int r = 0; r < 8; ++r) f[r] = (__bf16)xr[ks * 16 + hi * 8 + r];
            B[ks] = f;
        }
        #pragma unroll
        for (int ct = 0; ct < 2; ++ct)
            #pragma unroll
            for (int q = 0; q < 4; ++q) {
                bf16x4 t;
                #pragma unroll
                for (int j = 0; j < 4; ++j)
                    t[j] = (__bf16)xr[(sub * 2 + ct) * 32 + q * 8 + hi * 4 + j];
                X[ct][q] = t;
            }
    }
}

// One m-tile: prefetch next tile's frags, 18 MFMA, in-lane epilogue dot,
// hi-combine via shfl, stash partial in sArr[MT]. NO barrier, NO store here.
#define STEP(MT, BC, XC, BN, XN)                                                   \
  {                                                                                \
    if ((MT) + 1 < NT)                                                             \
      load_tile<PREP>(BN, XN, xq, x, rbase + (long)((MT) + 1) * 32 + b32, sub, hi);\
    f32x16 a0, a1;                                                                 \
    _Pragma("unroll")                                                              \
    for (int r = 0; r < 16; ++r) { a0[r] = 0.f; a1[r] = 0.f; }                     \
    _Pragma("unroll")                                                              \
    for (int ks = 0; ks < 8; ++ks) {                                               \
      a0 = __builtin_amdgcn_mfma_f32_32x32x16_bf16(A[0][ks], BC[ks], a0, 0, 0, 0); \
      a1 = __builtin_amdgcn_mfma_f32_32x32x16_bf16(A[1][ks], BC[ks], a1, 0, 0, 0); \
    }                                                                              \
    a0 = __builtin_amdgcn_mfma_f32_32x32x16_bf16(A[0][8], B8c, a0, 0, 0, 0);       \
    a1 = __builtin_amdgcn_mfma_f32_32x32x16_bf16(A[1][8], B8c, a1, 0, 0, 0);       \
    float s = 0.f;                                                                 \
    _Pragma("unroll")                                                              \
    for (int q = 0; q < 4; ++q)                                                    \
      _Pragma("unroll")                                                            \
      for (int j = 0; j < 4; ++j) {                                                \
        s += a0[q * 4 + j] * (float)XC[0][q][j];                                   \
        s += a1[q * 4 + j] * (float)XC[1][q][j];                                   \
      }                                                                            \
    s += __shfl_xor(s, 32);                                                        \
    sArr[MT] = s;                                                                  \
  }

// Block = 2 waves = 1 pair. Pair owns (o, 512-row run). Wave sub owns i-half;
// A = Wq~ rows stationary in regs. Barrier-free main loop; one combine at end.
template<int PREP>
__global__ __launch_bounds__(128, 2) void quad3(
    const float* __restrict__ x, const float* __restrict__ W,
    const __bf16* __restrict__ xq, const __bf16* __restrict__ Wq,
    const float* __restrict__ bias, float* __restrict__ out)
{
    __shared__ float red[2][NT][32];     // [sub][tile][b] partials

    const int tid  = threadIdx.x;
    const int lane = tid & 63;
    const int sub  = tid >> 6;           // wave id = i-half (0: i<64, 1: i>=64)
    const int b32  = lane & 31, hi = lane >> 5;

    // XCD-aware bijective swizzle (1024 = 8*128): o fastest within an XCD
    const int bid = blockIdx.x;
    const int swz = (bid & 7) * 128 + (bid >> 3);
    const int o   = swz & 31;
    const long rbase = (long)(swz >> 5) * 512;   // 32 runs of 512 rows

    const float bias_o = bias[o];

    // ---- stationary A fragments: lane l -> row i = l&31, k = hi*8 + r ----
    bf16x8 A[2][9];
    #pragma unroll
    for (int ct = 0; ct < 2; ++ct) {
        const int i = (sub * 2 + ct) * 32 + b32;
        if (PREP) {
            const __bf16* base = Wq + ((size_t)o * 128 + i) * KE + hi * 8;
            #pragma unroll
            for (int ks = 0; ks < 9; ++ks)
                A[ct][ks] = *reinterpret_cast<const bf16x8*>(base + ks * 16);
        } else {
            const float* wr = W + (size_t)o * WROW + (size_t)i * K129;
            #pragma unroll
            for (int ks = 0; ks < 8; ++ks) {
                bf16x8 f;
                #pragma unroll
                for (int r = 0; r < 8; ++r) f[r] = (__bf16)wr[ks * 16 + hi * 8 + r];
                A[ct][ks] = f;
            }
            bf16x8 f;
            #pragma unroll
            for (int r = 0; r < 8; ++r) f[r] = (__bf16)0.f;
            if (hi == 0) f[0] = (__bf16)wr[128];         // wlin at k=128
            A[ct][8] = f;
        }
    }

    // ---- constant ks=8 B fragment: x~[b,128]=1, 129..143=0 ----
    bf16x8 B8c;
    #pragma unroll
    for (int r = 0; r < 8; ++r) B8c[r] = (__bf16)0.f;
    if (hi == 0) B8c[0] = (__bf16)1.0f;

    float sArr[NT];
    bf16x8 Bf0[8], Bf1[8];
    bf16x4 Xe0[2][4], Xe1[2][4];

    load_tile<PREP>(Bf0, Xe0, xq, x, rbase + b32, sub, hi);

    #pragma unroll
    for (int m2 = 0; m2 < NT / 2; ++m2) {
        STEP(m2 * 2,     Bf0, Xe0, Bf1, Xe1);
        STEP(m2 * 2 + 1, Bf1, Xe1, Bf0, Xe0);
    }

    // ---- one-time cross-wave combine ----
    if (hi == 0) {
        #pragma unroll
        for (int mt = 0; mt < NT; ++mt) red[sub][mt][b32] = sArr[mt];
    }
    __syncthreads();
    if (sub == 0) {
        #pragma unroll
        for (int m = 0; m < NT / 2; ++m) {
            int mt = m * 2 + hi;
            out[(rbase + (long)mt * 32 + b32) * N_OUT + o] =
                red[0][mt][b32] + red[1][mt][b32] + bias_o;
        }
    }
}

extern "C" void kernel_launch(void* const* d_in, const int* in_sizes, int n_in,
                              void* d_out, int out_size, void* d_ws, size_t ws_size,
                              hipStream_t stream) {
    const float* x    = (const float*)d_in[0];
    const float* W    = (const float*)d_in[1];
    const float* bias = (const float*)d_in[2];
    float* out = (float*)d_out;

    const size_t need = (size_t)(XQ_ELEMS + WQ_ELEMS) * sizeof(__bf16);  // ~5.3 MB
    if (ws_size >= need) {
        __bf16* xq = (__bf16*)d_ws;
        __bf16* Wq = xq + XQ_ELEMS;
        prep_x<<<1024, 256, 0, stream>>>(x, xq);
        prep_w<<<512,  256, 0, stream>>>(W, Wq);
        quad3<1><<<1024, 128, 0, stream>>>(x, W, xq, Wq, bias, out);
    } else {
        quad3<0><<<1024, 128, 0, stream>>>(x, W, (const __bf16*)nullptr,
                                           (const __bf16*)nullptr, bias, out);
    }
}

// Round 4
// 31.724 us; speedup vs baseline: 2.3426x; 2.3426x over previous
//
#include <hip/hip_runtime.h>

typedef __attribute__((ext_vector_type(8)))  __bf16 bf16x8;
typedef __attribute__((ext_vector_type(4)))  __bf16 bf16x4;
typedef __attribute__((ext_vector_type(16))) float  f32x16;
typedef unsigned int uint32;

#define D_IN  128
#define N_OUT 32
#define K129  129
#define WROW  16512          // 128*129 floats per W row
#define KE    144            // extended K for W: col 128 = wlin, 129..143 = 0
#define NT    8              // m-tiles (32 rows) per block = 256-row run
#define XQ_ELEMS (16384 * 128)
#define WQ_ELEMS (32 * 128 * KE)

// ---- fused prep (one launch): x -> bf16 [16384][128]; W -> bf16 [32][128][144] ----
__global__ void prep(const float* __restrict__ x, const float* __restrict__ W,
                     __bf16* __restrict__ xq, __bf16* __restrict__ Wq) {
    int t = blockIdx.x * 256 + threadIdx.x;          // 1024*256 = 262144 threads
    {
        const float4* s = reinterpret_cast<const float4*>(x) + (size_t)t * 2;
        float4 a = s[0], b = s[1];
        bf16x8 v = { (__bf16)a.x, (__bf16)a.y, (__bf16)a.z, (__bf16)a.w,
                     (__bf16)b.x, (__bf16)b.y, (__bf16)b.z, (__bf16)b.w };
        reinterpret_cast<bf16x8*>(xq)[t] = v;
    }
    for (int e = t; e < WQ_ELEMS; e += 262144) {
        int oi = e / KE, k = e - oi * KE;            // oi = o*128 + i
        int o = oi >> 7, i = oi & 127;
        float v = (k <= D_IN) ? W[o * WROW + i * K129 + k] : 0.f;  // k==128 -> wlin
        Wq[e] = (__bf16)v;
    }
}

// LDS tile layout: [32 rows][16 chunks of 16B], chunk-XOR swizzled:
// logical (r, c) lives at phys chunk r*16 + (c ^ (r&15)).  Staged via
// global_load_lds with pre-swizzled SOURCE (linear dest), read with the XOR.

// issue next tile's staging (no waits here)
#define STAGE(BUF, T)                                                              \
  do {                                                                             \
    if (PREP) {                                                                    \
      __builtin_amdgcn_global_load_lds(                                            \
        (const __attribute__((address_space(1))) uint32*)                          \
          (xq + ((rbase + (long)(T) * 32 + r0s) * D_IN + c0s * 8)),                \
        (__attribute__((address_space(3))) uint32*)(&tile[BUF][wave * 1024]),      \
        16, 0, 0);                                                                 \
      __builtin_amdgcn_global_load_lds(                                            \
        (const __attribute__((address_space(1))) uint32*)                          \
          (xq + ((rbase + (long)(T) * 32 + r1s) * D_IN + c1s * 8)),                \
        (__attribute__((address_space(3))) uint32*)(&tile[BUF][wave * 1024 + 512]),\
        16, 0, 0);                                                                 \
    } else {                                                                       \
      const float* s0 = x + (rbase + (long)(T) * 32 + r0s) * D_IN + c0s * 8;       \
      const float* s1 = x + (rbase + (long)(T) * 32 + r1s) * D_IN + c1s * 8;       \
      float4 a0 = *(const float4*)s0, a1 = *(const float4*)(s0 + 4);               \
      float4 b0 = *(const float4*)s1, b1 = *(const float4*)(s1 + 4);               \
      bf16x8 v0 = { (__bf16)a0.x,(__bf16)a0.y,(__bf16)a0.z,(__bf16)a0.w,           \
                    (__bf16)a1.x,(__bf16)a1.y,(__bf16)a1.z,(__bf16)a1.w };         \
      bf16x8 v1 = { (__bf16)b0.x,(__bf16)b0.y,(__bf16)b0.z,(__bf16)b0.w,           \
                    (__bf16)b1.x,(__bf16)b1.y,(__bf16)b1.z,(__bf16)b1.w };         \
      *(bf16x8*)&tile[BUF][(size_t)p0 * 8] = v0;                                   \
      *(bf16x8*)&tile[BUF][(size_t)p1 * 8] = v1;                                   \
    }                                                                              \
  } while (0)

// one m-tile: 8 swizzled ds_read_b128 -> 18 MFMA, Xe via 8 ds_read_b64, dot, shfl
#define COMPUTE(BUF, MT)                                                           \
  {                                                                                \
    const char* tb = (const char*)&tile[BUF][0];                                   \
    f32x16 a0, a1;                                                                 \
    _Pragma("unroll")                                                              \
    for (int r = 0; r < 16; ++r) { a0[r] = 0.f; a1[r] = 0.f; }                     \
    _Pragma("unroll")                                                              \
    for (int ks = 0; ks < 8; ++ks) {                                               \
      bf16x8 bfr = *reinterpret_cast<const bf16x8*>(tb + laneB[ks]);               \
      a0 = __builtin_amdgcn_mfma_f32_32x32x16_bf16(A[0][ks], bfr, a0, 0, 0, 0);    \
      a1 = __builtin_amdgcn_mfma_f32_32x32x16_bf16(A[1][ks], bfr, a1, 0, 0, 0);    \
    }                                                                              \
    a0 = __builtin_amdgcn_mfma_f32_32x32x16_bf16(A[0][8], B8c, a0, 0, 0, 0);       \
    a1 = __builtin_amdgcn_mfma_f32_32x32x16_bf16(A[1][8], B8c, a1, 0, 0, 0);       \
    bf16x4 xe0[4], xe1[4];                                                         \
    _Pragma("unroll")                                                              \
    for (int q = 0; q < 4; ++q) {                                                  \
      xe0[q] = *reinterpret_cast<const bf16x4*>(tb + laneX[0][q]);                 \
      xe1[q] = *reinterpret_cast<const bf16x4*>(tb + laneX[1][q]);                 \
    }                                                                              \
    float s0 = 0.f, s1 = 0.f;                                                      \
    _Pragma("unroll")                                                              \
    for (int q = 0; q < 4; ++q)                                                    \
      _Pragma("unroll")                                                            \
      for (int j = 0; j < 4; ++j) {                                                \
        s0 += a0[q * 4 + j] * (float)xe0[q][j];                                    \
        s1 += a1[q * 4 + j] * (float)xe1[q][j];                                    \
      }                                                                            \
    float s = s0 + s1;                                                             \
    s += __shfl_xor(s, 32);                                                        \
    sArr[MT] = s;                                                                  \
  }

// Block = 4 waves = 2 o's x 2 i-halves over one 256-row run. x staged in LDS
// (shared by all 4 waves); W stationary in regs; 2-phase double buffer.
template<int PREP>
__global__ __launch_bounds__(256, 2) void quad4(
    const float* __restrict__ x, const float* __restrict__ W,
    const __bf16* __restrict__ xq, const __bf16* __restrict__ Wq,
    const float* __restrict__ bias, float* __restrict__ out)
{
    __shared__ __align__(16) __bf16 tile[2][32 * 128];   // 2 x 8KB, swizzled
    __shared__ float red[2][2][NT][32];                  // [pair][sub][mt][b] 4KB

    const int tid  = threadIdx.x;
    const int lane = tid & 63;
    const int wave = tid >> 6;              // 0..3
    const int pairId = wave >> 1;           // which o of the block's 2
    const int sub  = wave & 1;              // i-half (0: i<64, 1: i>=64)
    const int b32  = lane & 31, hi = lane >> 5;

    // grid 1024 = 8 XCD x (16 o-pairs x 8 runs): same-XCD blocks share x runs
    const int bid = blockIdx.x;
    const int xcd = bid & 7, idx = bid >> 3;
    const int opair = idx & 15;
    const int run = xcd * 8 + (idx >> 4);   // 0..63
    const int o = opair * 2 + pairId;
    const long rbase = (long)run * (NT * 32);
    const float bias_o = bias[o];

    // ---- stationary A fragments: lane -> row i = (sub*2+ct)*32 + b32, k = hi*8+r ----
    bf16x8 A[2][9];
    #pragma unroll
    for (int ct = 0; ct < 2; ++ct) {
        const int i = (sub * 2 + ct) * 32 + b32;
        if (PREP) {
            const __bf16* base = Wq + ((size_t)o * 128 + i) * KE + hi * 8;
            #pragma unroll
            for (int ks = 0; ks < 9; ++ks)
                A[ct][ks] = *reinterpret_cast<const bf16x8*>(base + ks * 16);
        } else {
            const float* wr = W + (size_t)o * WROW + (size_t)i * K129;
            #pragma unroll
            for (int ks = 0; ks < 8; ++ks) {
                bf16x8 f;
                #pragma unroll
                for (int r = 0; r < 8; ++r) f[r] = (__bf16)wr[ks * 16 + hi * 8 + r];
                A[ct][ks] = f;
            }
            bf16x8 f;
            #pragma unroll
            for (int r = 0; r < 8; ++r) f[r] = (__bf16)0.f;
            if (hi == 0) f[0] = (__bf16)wr[128];
            A[ct][8] = f;
        }
    }

    // constant ks=8 B fragment: x~[b,128]=1, rest 0
    bf16x8 B8c;
    #pragma unroll
    for (int r = 0; r < 8; ++r) B8c[r] = (__bf16)0.f;
    if (hi == 0) B8c[0] = (__bf16)1.0f;

    // staging lane assignment: thread -> phys chunks {wave*128+lane, +64}
    const int p0 = wave * 128 + lane;
    const int r0s = p0 >> 4, c0s = (p0 & 15) ^ (r0s & 15);
    const int p1 = p0 + 64;
    const int r1s = p1 >> 4, c1s = (p1 & 15) ^ (r1s & 15);

    // swizzled ds_read byte offsets (per-lane, tile-independent)
    const int rm = b32 & 15;
    int laneB[8];
    #pragma unroll
    for (int ks = 0; ks < 8; ++ks)
        laneB[ks] = b32 * 256 + (((ks * 2 + hi) ^ rm) << 4);
    int laneX[2][4];
    #pragma unroll
    for (int ct = 0; ct < 2; ++ct)
        #pragma unroll
        for (int q = 0; q < 4; ++q)
            laneX[ct][q] = b32 * 256 + ((((sub * 2 + ct) * 4 + q) ^ rm) << 4) + hi * 8;

    float sArr[NT];

    STAGE(0, 0);
    __syncthreads();                       // drains stage (vmcnt/lgkm in barrier)

    #pragma unroll
    for (int t2 = 0; t2 < NT / 2; ++t2) {
        if (t2 * 2 + 1 < NT) STAGE(1, t2 * 2 + 1);
        COMPUTE(0, t2 * 2);
        __syncthreads();
        if (t2 * 2 + 2 < NT) STAGE(0, t2 * 2 + 2);
        COMPUTE(1, t2 * 2 + 1);
        __syncthreads();
    }

    // ---- one-time cross-sub combine + store ----
    if (hi == 0) {
        #pragma unroll
        for (int mt = 0; mt < NT; ++mt) red[pairId][sub][mt][b32] = sArr[mt];
    }
    __syncthreads();
    if (sub == 0) {
        #pragma unroll
        for (int m = 0; m < NT / 2; ++m) {
            int mt = m * 2 + hi;
            out[(rbase + (long)mt * 32 + b32) * N_OUT + o] =
                red[pairId][0][mt][b32] + red[pairId][1][mt][b32] + bias_o;
        }
    }
}

extern "C" void kernel_launch(void* const* d_in, const int* in_sizes, int n_in,
                              void* d_out, int out_size, void* d_ws, size_t ws_size,
                              hipStream_t stream) {
    const float* x    = (const float*)d_in[0];
    const float* W    = (const float*)d_in[1];
    const float* bias = (const float*)d_in[2];
    float* out = (float*)d_out;

    const size_t need = (size_t)(XQ_ELEMS + WQ_ELEMS) * sizeof(__bf16);  // ~5.4 MB
    if (ws_size >= need) {
        __bf16* xq = (__bf16*)d_ws;
        __bf16* Wq = xq + XQ_ELEMS;
        prep<<<1024, 256, 0, stream>>>(x, W, xq, Wq);
        quad4<1><<<1024, 256, 0, stream>>>(x, W, xq, Wq, bias, out);
    } else {
        quad4<0><<<1024, 256, 0, stream>>>(x, W, (const __bf16*)nullptr,
                                           (const __bf16*)nullptr, bias, out);
    }
}

// Round 5
// 27.786 us; speedup vs baseline: 2.6746x; 1.1417x over previous
//
#include <hip/hip_runtime.h>

typedef __attribute__((ext_vector_type(8)))  __bf16 bf16x8;
typedef __attribute__((ext_vector_type(16))) float  f32x16;
typedef unsigned int uint32;

#define D_IN  128
#define N_OUT 32
#define K129  129
#define WROW  16512          // 128*129 floats per W row
#define KE    144            // extended K for W: col 128 = wlin, 129..143 = 0
#define NT    8              // m-tiles (32 rows) per block = 256-row run
#define XQ_ELEMS (16384 * 128)
#define WQ_ELEMS (32 * 128 * KE)

// slot -> i permutation within each 32-row block: makes each lane's acc rows
// line up with the 8-elem col chunks its own B-fragments hold.
__host__ __device__ __forceinline__ int permSlot(int s) {
    int q = s >> 3, h = (s >> 2) & 1, j = s & 3;
    return 16 * (q >> 1) + 8 * h + 4 * (q & 1) + j;
}

// ---- fused prep: x -> bf16 [16384][128]; W -> bf16 [32][128 slots][144] ----
__global__ void prep(const float* __restrict__ x, const float* __restrict__ W,
                     __bf16* __restrict__ xq, __bf16* __restrict__ Wq) {
    int t = blockIdx.x * 256 + threadIdx.x;          // 1024*256 = 262144 threads
    {
        const float4* s = reinterpret_cast<const float4*>(x) + (size_t)t * 2;
        float4 a = s[0], b = s[1];
        bf16x8 v = { (__bf16)a.x, (__bf16)a.y, (__bf16)a.z, (__bf16)a.w,
                     (__bf16)b.x, (__bf16)b.y, (__bf16)b.z, (__bf16)b.w };
        reinterpret_cast<bf16x8*>(xq)[t] = v;
    }
    for (int e = t; e < WQ_ELEMS; e += 262144) {
        int oi = e / KE, k = e - oi * KE;            // oi = o*128 + slot_g
        int o = oi >> 7, sg = oi & 127;
        int i = (sg & ~31) + permSlot(sg & 31);      // permuted source row
        float v = (k <= D_IN) ? W[o * WROW + i * K129 + k] : 0.f;  // k==128 -> wlin
        Wq[e] = (__bf16)v;
    }
}

// LDS tile: [32 rows][16 chunks of 16B], chunk-XOR swizzled (phys c = log c ^ (r&15)).
// Staged via global_load_lds with pre-swizzled SOURCE (linear dest).
#define STAGE(BUF, T)                                                              \
  do {                                                                             \
    if (PREP) {                                                                    \
      __builtin_amdgcn_global_load_lds(                                            \
        (const __attribute__((address_space(1))) uint32*)                          \
          (xq + ((rbase + (long)(T) * 32 + r0s) * D_IN + c0s * 8)),                \
        (__attribute__((address_space(3))) uint32*)(&tile[BUF][wave * 1024]),      \
        16, 0, 0);                                                                 \
      __builtin_amdgcn_global_load_lds(                                            \
        (const __attribute__((address_space(1))) uint32*)                          \
          (xq + ((rbase + (long)(T) * 32 + r1s) * D_IN + c1s * 8)),                \
        (__attribute__((address_space(3))) uint32*)(&tile[BUF][wave * 1024 + 512]),\
        16, 0, 0);                                                                 \
    } else {                                                                       \
      const float* s0 = x + (rbase + (long)(T) * 32 + r0s) * D_IN + c0s * 8;       \
      const float* s1 = x + (rbase + (long)(T) * 32 + r1s) * D_IN + c1s * 8;       \
      float4 a0 = *(const float4*)s0, a1 = *(const float4*)(s0 + 4);               \
      float4 b0 = *(const float4*)s1, b1 = *(const float4*)(s1 + 4);               \
      bf16x8 v0 = { (__bf16)a0.x,(__bf16)a0.y,(__bf16)a0.z,(__bf16)a0.w,           \
                    (__bf16)a1.x,(__bf16)a1.y,(__bf16)a1.z,(__bf16)a1.w };         \
      bf16x8 v1 = { (__bf16)b0.x,(__bf16)b0.y,(__bf16)b0.z,(__bf16)b0.w,           \
                    (__bf16)b1.x,(__bf16)b1.y,(__bf16)b1.z,(__bf16)b1.w };         \
      *(bf16x8*)&tile[BUF][(size_t)p0 * 8] = v0;                                   \
      *(bf16x8*)&tile[BUF][(size_t)p1 * 8] = v1;                                   \
    }                                                                              \
  } while (0)

// One m-tile: 8 swizzled ds_read_b128 -> 4 blocks x 9 MFMA; epilogue dot uses
// the SAME B-frag registers (permuted W makes indices line up). Store per tile.
#define COMPUTE(BUF, MT)                                                           \
  {                                                                                \
    const char* tb = (const char*)&tile[BUF][0];                                   \
    bf16x8 Bf[8];                                                                  \
    _Pragma("unroll")                                                              \
    for (int ks = 0; ks < 8; ++ks)                                                 \
      Bf[ks] = *reinterpret_cast<const bf16x8*>(tb + laneB[ks]);                   \
    float s = 0.f;                                                                 \
    _Pragma("unroll")                                                              \
    for (int ct = 0; ct < 4; ++ct) {                                               \
      f32x16 a;                                                                    \
      _Pragma("unroll")                                                            \
      for (int r = 0; r < 16; ++r) a[r] = 0.f;                                     \
      _Pragma("unroll")                                                            \
      for (int ks = 0; ks < 8; ++ks)                                               \
        a = __builtin_amdgcn_mfma_f32_32x32x16_bf16(A[ct][ks], Bf[ks], a, 0, 0, 0);\
      a = __builtin_amdgcn_mfma_f32_32x32x16_bf16(A[ct][8], B8c, a, 0, 0, 0);      \
      _Pragma("unroll")                                                            \
      for (int q = 0; q < 4; ++q)                                                  \
        _Pragma("unroll")                                                          \
        for (int j = 0; j < 4; ++j)                                                \
          s += a[q * 4 + j] * (float)Bf[2 * ct + (q >> 1)][4 * (q & 1) + j];       \
    }                                                                              \
    s += __shfl_xor(s, 32);                                                        \
    if (hi == 0)                                                                   \
      out[(rbase + (long)(MT) * 32 + b32) * N_OUT + o] = s + bias_o;               \
  }

// Block = 4 waves = 4 o's over one shared 256-row run. Each wave: full 128-i
// for its o (A stationary, 144 VGPR); x double-buffered in LDS.
template<int PREP>
__global__ __launch_bounds__(256, 2) void quad5(
    const float* __restrict__ x, const float* __restrict__ W,
    const __bf16* __restrict__ xq, const __bf16* __restrict__ Wq,
    const float* __restrict__ bias, float* __restrict__ out)
{
    __shared__ __align__(16) __bf16 tile[2][32 * 128];   // 2 x 8KB, swizzled

    const int tid  = threadIdx.x;
    const int lane = tid & 63;
    const int wave = tid >> 6;              // 0..3 = o within group
    const int b32  = lane & 31, hi = lane >> 5;

    // grid 512 = 8 XCD x (8 runs x 8 o-groups): same-XCD blocks share x runs
    const int bid = blockIdx.x;
    const int xcd = bid & 7, idx = bid >> 3;
    const int run = xcd * 8 + (idx & 7);    // 0..63
    const int og  = idx >> 3;               // 0..7
    const int o   = og * 4 + wave;
    const long rbase = (long)run * (NT * 32);
    const float bias_o = bias[o];

    // ---- stationary A fragments: lane -> slot row ct*32 + b32, k = hi*8 + r ----
    bf16x8 A[4][9];
    #pragma unroll
    for (int ct = 0; ct < 4; ++ct) {
        if (PREP) {
            const __bf16* base = Wq + ((size_t)o * 128 + ct * 32 + b32) * KE + hi * 8;
            #pragma unroll
            for (int ks = 0; ks < 9; ++ks)
                A[ct][ks] = *reinterpret_cast<const bf16x8*>(base + ks * 16);
        } else {
            const int i = ct * 32 + permSlot(b32);
            const float* wr = W + (size_t)o * WROW + (size_t)i * K129;
            #pragma unroll
            for (int ks = 0; ks < 8; ++ks) {
                bf16x8 f;
                #pragma unroll
                for (int r = 0; r < 8; ++r) f[r] = (__bf16)wr[ks * 16 + hi * 8 + r];
                A[ct][ks] = f;
            }
            bf16x8 f;
            #pragma unroll
            for (int r = 0; r < 8; ++r) f[r] = (__bf16)0.f;
            if (hi == 0) f[0] = (__bf16)wr[128];         // wlin at k=128
            A[ct][8] = f;
        }
    }

    // constant ks=8 B fragment: x~[b,128]=1, rest 0
    bf16x8 B8c;
    #pragma unroll
    for (int r = 0; r < 8; ++r) B8c[r] = (__bf16)0.f;
    if (hi == 0) B8c[0] = (__bf16)1.0f;

    // staging mapping: thread -> phys chunks {wave*128+lane, +64}; src un-swizzled
    const int p0 = wave * 128 + lane;
    const int r0s = p0 >> 4, c0s = (p0 & 15) ^ (r0s & 15);
    const int p1 = p0 + 64;
    const int r1s = p1 >> 4, c1s = (p1 & 15) ^ (r1s & 15);

    // swizzled ds_read byte offsets (row = b32, logical chunk 2ks+hi)
    const int rm = b32 & 15;
    int laneB[8];
    #pragma unroll
    for (int ks = 0; ks < 8; ++ks)
        laneB[ks] = b32 * 256 + (((ks * 2 + hi) ^ rm) << 4);

    STAGE(0, 0);
    __syncthreads();

    #pragma unroll
    for (int t2 = 0; t2 < NT / 2; ++t2) {
        if (t2 * 2 + 1 < NT) STAGE(1, t2 * 2 + 1);
        COMPUTE(0, t2 * 2);
        __syncthreads();
        if (t2 * 2 + 2 < NT) STAGE(0, t2 * 2 + 2);
        COMPUTE(1, t2 * 2 + 1);
        __syncthreads();
    }
}

extern "C" void kernel_launch(void* const* d_in, const int* in_sizes, int n_in,
                              void* d_out, int out_size, void* d_ws, size_t ws_size,
                              hipStream_t stream) {
    const float* x    = (const float*)d_in[0];
    const float* W    = (const float*)d_in[1];
    const float* bias = (const float*)d_in[2];
    float* out = (float*)d_out;

    const size_t need = (size_t)(XQ_ELEMS + WQ_ELEMS) * sizeof(__bf16);  // ~5.4 MB
    if (ws_size >= need) {
        __bf16* xq = (__bf16*)d_ws;
        __bf16* Wq = xq + XQ_ELEMS;
        prep<<<1024, 256, 0, stream>>>(x, W, xq, Wq);
        quad5<1><<<512, 256, 0, stream>>>(x, W, xq, Wq, bias, out);
    } else {
        quad5<0><<<512, 256, 0, stream>>>(x, W, (const __bf16*)nullptr,
                                          (const __bf16*)nullptr, bias, out);
    }
}